// Round 7
// baseline (476.689 us; speedup 1.0000x reference)
//
#include <hip/hip_runtime.h>
#include <math.h>

typedef _Float16 half8 __attribute__((ext_vector_type(8)));
typedef float floatx4 __attribute__((ext_vector_type(4)));

typedef const uint32_t __attribute__((address_space(1)))* gp1_t;
typedef uint32_t __attribute__((address_space(3)))* lp3_t;
#define GLDS16(g, l) __builtin_amdgcn_global_load_lds((gp1_t)(const void*)(g), (lp3_t)(void*)(l), 16, 0, 0)

#define BK 32

#define BARRIER() __builtin_amdgcn_s_barrier()
#define VM4()     asm volatile("s_waitcnt vmcnt(4)" ::: "memory")

// Bijective XCD-aware remap of linearized workgroup id (m204 form; identity when nwg<8).
__device__ inline int xcd_swz(int wg, int nwg)
{
    int q = nwg >> 3, r = nwg & 7;
    int xcd = wg & 7, idx = wg >> 3;
    return (xcd < r) ? (xcd * (q + 1) + idx) : (r * (q + 1) + (xcd - r) * q + idx);
}

// ---------------- 128x128 m97-structure kernel (G4 / G9 / G10) ----------------
// C[m][n] = alpha * sum_k A[m][k]*B[n][k]; A,B f16 k-contiguous.
__global__ __launch_bounds__(256) void gemm_fast(
    const _Float16* __restrict__ A, const _Float16* __restrict__ B,
    float* __restrict__ Cf, _Float16* __restrict__ Ch,
    float* __restrict__ Cx, _Float16* __restrict__ Cy,
    int Kc, long lda, long ldb, long ldcf, long ldch,
    int cmap, long cf_lo, long cf_hi, float alpha, int nh, int nsk, int epi_mode,
    long aoff_b, long aoff_h, long boff_b, long boff_h,
    long coff_b, long coff_h, long coff_s)
{
    __shared__ __align__(16) _Float16 As[128 * BK];
    __shared__ __align__(16) _Float16 Bs[128 * BK];

    const int z = blockIdx.z;
    const int hs = nh * nsk;
    const int zb = z / hs;
    const int rr = z % hs;
    const int zh = rr / nsk;
    const int ks = rr % nsk;

    const _Float16* Ab = A + (long)zb * aoff_b + (long)zh * aoff_h + (long)ks * Kc;
    const _Float16* Bb = B + (long)zb * boff_b + (long)zh * boff_h + (long)ks * Kc;
    const long cofs = (long)zb * coff_b + (long)zh * coff_h + (long)ks * coff_s;

    const int nwg = gridDim.x * gridDim.y;
    const int swz = xcd_swz(blockIdx.y * gridDim.x + blockIdx.x, nwg);
    const long m0 = (long)(swz / gridDim.x) * 128;
    const long n0 = (long)(swz % gridDim.x) * 128;
    const int t = threadIdx.x;
    const int wave = t >> 6, lane = t & 63;
    const int lr = lane & 15, lq = lane >> 4;
    const int wm = (wave & 1) * 64, wn = (wave >> 1) * 64;

    const int c0 = wave * 64 + lane;
    const int c1 = c0 + 256;
    const _Float16* ga0 = Ab + (m0 + (c0 >> 2)) * lda + (c0 & 3) * 8;
    const _Float16* ga1 = Ab + (m0 + (c1 >> 2)) * lda + (c1 & 3) * 8;
    const _Float16* gb0 = Bb + (n0 + (c0 >> 2)) * ldb + (c0 & 3) * 8;
    const _Float16* gb1 = Bb + (n0 + (c1 >> 2)) * ldb + (c1 & 3) * 8;
    _Float16* lA0 = As + wave * 512;
    _Float16* lA1 = As + 2048 + wave * 512;
    _Float16* lB0 = Bs + wave * 512;
    _Float16* lB1 = Bs + 2048 + wave * 512;

    floatx4 acc[4][4];
    #pragma unroll
    for (int i = 0; i < 4; ++i)
        #pragma unroll
        for (int j = 0; j < 4; ++j) acc[i][j] = (floatx4){0.f, 0.f, 0.f, 0.f};

    for (int k0 = 0; k0 < Kc; k0 += BK) {
        GLDS16(ga0, lA0); GLDS16(ga1, lA1);
        GLDS16(gb0, lB0); GLDS16(gb1, lB1);
        ga0 += BK; ga1 += BK; gb0 += BK; gb1 += BK;
        __syncthreads();

        half8 a[4], b[4];
        #pragma unroll
        for (int i = 0; i < 4; ++i) a[i] = *(const half8*)(As + (wm + i * 16 + lr) * BK + lq * 8);
        #pragma unroll
        for (int j = 0; j < 4; ++j) b[j] = *(const half8*)(Bs + (wn + j * 16 + lr) * BK + lq * 8);
        #pragma unroll
        for (int i = 0; i < 4; ++i)
            #pragma unroll
            for (int j = 0; j < 4; ++j)
                acc[i][j] = __builtin_amdgcn_mfma_f32_16x16x32_f16(a[i], b[j], acc[i][j], 0, 0, 0);
        __syncthreads();
    }

    // C/D layout: col = lane&15, row = (lane>>4)*4 + reg
    if (epi_mode == 0) {
        #pragma unroll
        for (int i = 0; i < 4; ++i)
            #pragma unroll
            for (int j = 0; j < 4; ++j)
                #pragma unroll
                for (int r = 0; r < 4; ++r) {
                    long row = m0 + wm + i * 16 + lq * 4 + r;
                    long col = n0 + wn + j * 16 + lr;
                    float v = alpha * acc[i][j][r];
                    if (Ch) {
                        long cm = cmap ? ((col >> 6) * 128 + (col & 63)) : col;
                        Ch[cofs + row * ldch + cm] = (_Float16)v;
                    }
                    if (Cf && col >= cf_lo && col < cf_hi)
                        Cf[cofs + row * ldcf + (col - cf_lo)] = v;
                }
    } else if (epi_mode == 1) {
        const int nb = (int)n0 + wn;
        if (nb < 2048) {
            #pragma unroll
            for (int i = 0; i < 4; ++i)
                #pragma unroll
                for (int j = 0; j < 4; ++j)
                    #pragma unroll
                    for (int r = 0; r < 4; ++r) {
                        long row = m0 + wm + i * 16 + lq * 4 + r;
                        long col = n0 + wn + j * 16 + lr;
                        float v = acc[i][j][r];
                        Ch[row * 2048 + col] = (_Float16)v;
                        if (nb < 1024) Cf[row * 1024 + col] = v;
                    }
        } else {
            const int h = (nb - 2048) >> 6;
            const float invf = powf(10000.0f, -(float)lr / 16.0f);
            #pragma unroll
            for (int i = 0; i < 4; ++i)
                #pragma unroll
                for (int r = 0; r < 4; ++r) {
                    long row = m0 + wm + i * 16 + lq * 4 + r;
                    int s = (int)row & 2047;
                    float ang = ((float)s / 40.0f) * invf;
                    float cv = cosf(ang), sv = sinf(ang);
                    float v0 = acc[i][0][r], v1 = acc[i][1][r];
                    float y[4] = { v0 * cv - v1 * sv, v1 * cv + v0 * sv,
                                   acc[i][2][r], acc[i][3][r] };
                    #pragma unroll
                    for (int j = 0; j < 4; ++j) {
                        int d = j * 16 + lr;
                        Cx[row * 1024 + h * 64 + d] = y[j];
                        Cy[row * 2048 + h * 128 + 64 + d] = (_Float16)y[j];
                    }
                }
        }
    } else {  // epi_mode == 2
        if (zb == 0) {
            #pragma unroll
            for (int i = 0; i < 4; ++i)
                #pragma unroll
                for (int j = 0; j < 4; ++j)
                    #pragma unroll
                    for (int r = 0; r < 4; ++r) {
                        long row = m0 + wm + i * 16 + lq * 4 + r;
                        long col = n0 + wn + j * 16 + lr;
                        Ch[cofs + row * ldch + col] = (_Float16)acc[i][j][r];
                    }
        } else {
            const int mb = (int)m0 + wm;
            if (mb < 1024) {
                #pragma unroll
                for (int i = 0; i < 4; ++i)
                    #pragma unroll
                    for (int j = 0; j < 4; ++j)
                        #pragma unroll
                        for (int r = 0; r < 4; ++r) {
                            long u = m0 + wm + i * 16 + lq * 4 + r;
                            long col = n0 + wn + j * 16 + lr;
                            long qrow = ((u >> 6) << 7) + (u & 63);
                            Ch[cofs + qrow * 4096 + col] = (_Float16)acc[i][j][r];
                        }
            } else {
                const int h = (mb - 1024) >> 6;
                #pragma unroll
                for (int j = 0; j < 4; ++j)
                    #pragma unroll
                    for (int r = 0; r < 4; ++r) {
                        long col = n0 + wn + j * 16 + lr;
                        int s = (int)col & 2047;
                        int j16 = lq * 4 + r;
                        float ivf = powf(10000.0f, -(float)j16 / 16.0f);
                        float ang = ((float)s / 40.0f) * ivf;
                        float cv = cosf(ang), sv = sinf(ang);
                        float v0 = acc[0][j][r], v1 = acc[1][j][r];
                        float y[4] = { v0 * cv - v1 * sv, v1 * cv + v0 * sv,
                                       acc[2][j][r], acc[3][j][r] };
                        #pragma unroll
                        for (int i = 0; i < 4; ++i) {
                            int dd = i * 16 + lq * 4 + r;
                            long qrow = h * 128 + 64 + dd;
                            Ch[cofs + qrow * 4096 + col] = (_Float16)y[i];
                        }
                    }
            }
        }
    }
}

// ---------------- 128x128 counted-vmcnt kernel, 3 blocks/CU (G123/G5/G678/G11) ----------------
// grid = (N/128, M/128, z), block = 256 (4 waves, gemm_fast wave geometry -> epilogues verbatim).
// LDS: 3 slots x 16 KiB (A 8 units + B 8 units; unit = 16 rows x 32 k = 512 halves;
// lane l holds (row=l&15, k=(l>>4)*8..+7) at halves l*8) -> GLDS16 linear write from
// per-lane-permuted global src (m173), fragment ds_read_b128 at unit+lane*16B:
// conflict-free both sides (proven r2-r6, SQ_LDS_BANK_CONFLICT=0).
// Body tt: {4x stage tile tt+2 -> slot (tt+2)%3 ; 8x ds_read slot tt%3 ; 16 MFMA ;
// vmcnt(4) ; barrier}. VM4 leaves only tile tt+2's 4 loads in flight -> tile tt+1
// landed across all waves at barrier release; slot distance 2 mod 3 -> no overwrite
// race. vmcnt never 0 in-loop (T4). Tail tile indices clamp into [0,NT).
// 48 KiB LDS + launch_bounds(256,3) -> 3 blocks/CU; launcher keeps grids uniform
// multiples of 256 (768/1024/512/256) to avoid r6's grid-quantization loss.
__global__ __launch_bounds__(256, 3) void gemm128(
    const _Float16* __restrict__ A, const _Float16* __restrict__ B,
    float* __restrict__ Cf, _Float16* __restrict__ Ch,
    float* __restrict__ Cx, _Float16* __restrict__ Cy,
    int Kc, long lda, long ldb, long ldcf, long ldch,
    int cmap, long cf_lo, long cf_hi, float alpha, int nh, int nsk, int epi_mode,
    long aoff_b, long aoff_h, long boff_b, long boff_h,
    long coff_b, long coff_h, long coff_s)
{
    __shared__ __align__(16) _Float16 sm[24576];   // 48 KiB: 3 slots x (A 4K + B 4K halves)

    const int z = blockIdx.z;
    const int hs = nh * nsk;
    const int zb = z / hs;
    const int rr = z % hs;
    const int zh = rr / nsk;
    const int ks = rr % nsk;

    const _Float16* Ab = A + (long)zb * aoff_b + (long)zh * aoff_h + (long)ks * Kc;
    const _Float16* Bb = B + (long)zb * boff_b + (long)zh * boff_h + (long)ks * Kc;
    const long cofs = (long)zb * coff_b + (long)zh * coff_h + (long)ks * coff_s;

    const int nwg = gridDim.x * gridDim.y;
    const int swz = xcd_swz(blockIdx.y * gridDim.x + blockIdx.x, nwg);
    const long m0 = (long)(swz / gridDim.x) * 128;
    const long n0 = (long)(swz % gridDim.x) * 128;
    const int t = threadIdx.x;
    const int wave = t >> 6, lane = t & 63;
    const int lr = lane & 15, lq = lane >> 4;
    const int wm = (wave & 1) * 64, wn = (wave >> 1) * 64;   // gemm_fast geometry
    const int wmrb = (wave & 1) * 4, wnrb = (wave >> 1) * 4;
    const int NT = Kc >> 5;                                  // K-tiles of 32

    floatx4 acc[4][4];
    #pragma unroll
    for (int i = 0; i < 4; ++i)
        #pragma unroll
        for (int j = 0; j < 4; ++j) acc[i][j] = (floatx4){0.f, 0.f, 0.f, 0.f};

    // one staging issue per thread = 1 LDS unit per wave; q&1 -> unit wave*2+(q&1),
    // q>>1 -> A vs B. Tail tile index clamped into [0,NT).
#define ST(tt_, q_, sl_) do { \
        const int tcl_ = (tt_) < NT ? (tt_) : (tt_) - NT; \
        const int isB_ = (q_) >> 1; \
        const int u_ = wave * 2 + ((q_) & 1); \
        const long grow_ = (isB_ ? n0 : m0) + u_ * 16 + lr; \
        const _Float16* src_ = (isB_ ? Bb + grow_ * ldb : Ab + grow_ * lda) \
                               + (long)tcl_ * 32 + lq * 8; \
        _Float16* dst_ = sm + (sl_) * 8192 + isB_ * 4096 + u_ * 512; \
        GLDS16(src_, dst_); \
    } while (0)

#define LOADA(sl_) { _Pragma("unroll") \
    for (int i_ = 0; i_ < 4; ++i_) \
        aF[i_] = *(const half8*)(sm + (sl_) * 8192 + (wmrb + i_) * 512 + lane * 8); }
#define LOADB(sl_) { _Pragma("unroll") \
    for (int j_ = 0; j_ < 4; ++j_) \
        bF[j_] = *(const half8*)(sm + (sl_) * 8192 + 4096 + (wnrb + j_) * 512 + lane * 8); }
#define MFMA16() { _Pragma("unroll") \
    for (int i_ = 0; i_ < 4; ++i_) { _Pragma("unroll") \
        for (int j_ = 0; j_ < 4; ++j_) \
            acc[i_][j_] = __builtin_amdgcn_mfma_f32_16x16x32_f16(aF[i_], bF[j_], acc[i_][j_], 0, 0, 0); } }

    // prologue: stage tiles 0 (slot 0) and 1 (slot 1); drain to 4 => tile 0 landed
    ST(0, 0, 0); ST(0, 1, 0); ST(0, 2, 0); ST(0, 3, 0);
    ST(1, 0, 1); ST(1, 1, 1); ST(1, 2, 1); ST(1, 3, 1);
    VM4(); BARRIER();

    half8 aF[4], bF[4];
    int sc = 0, ss = 2;
    for (int tt = 0; tt < NT; ++tt) {
        ST(tt + 2, 0, ss); ST(tt + 2, 1, ss); ST(tt + 2, 2, ss); ST(tt + 2, 3, ss);
        LOADA(sc); LOADB(sc);
        __builtin_amdgcn_s_setprio(1); MFMA16(); __builtin_amdgcn_s_setprio(0);
        VM4();       // tile tt+1 landed (all waves after barrier)
        BARRIER();
        sc = (sc == 2) ? 0 : sc + 1;
        ss = (ss == 2) ? 0 : ss + 1;
    }
#undef ST
#undef LOADA
#undef LOADB
#undef MFMA16

    // ---- epilogues (verbatim gemm_fast; identical wave geometry) ----
    if (epi_mode == 0) {
        #pragma unroll
        for (int i = 0; i < 4; ++i)
            #pragma unroll
            for (int j = 0; j < 4; ++j)
                #pragma unroll
                for (int r = 0; r < 4; ++r) {
                    long row = m0 + wm + i * 16 + lq * 4 + r;
                    long col = n0 + wn + j * 16 + lr;
                    float v = alpha * acc[i][j][r];
                    if (Ch) {
                        long cm = cmap ? ((col >> 6) * 128 + (col & 63)) : col;
                        Ch[cofs + row * ldch + cm] = (_Float16)v;
                    }
                    if (Cf && col >= cf_lo && col < cf_hi)
                        Cf[cofs + row * ldcf + (col - cf_lo)] = v;
                }
    } else if (epi_mode == 1) {
        const int nb = (int)n0 + wn;
        if (nb < 2048) {
            #pragma unroll
            for (int i = 0; i < 4; ++i)
                #pragma unroll
                for (int j = 0; j < 4; ++j)
                    #pragma unroll
                    for (int r = 0; r < 4; ++r) {
                        long row = m0 + wm + i * 16 + lq * 4 + r;
                        long col = n0 + wn + j * 16 + lr;
                        float v = acc[i][j][r];
                        Ch[row * 2048 + col] = (_Float16)v;      // catA (c_kv|c_q)
                        if (nb < 1024) Cf[row * 1024 + col] = v; // c_kv fp32
                    }
        } else {
            const int h = (nb - 2048) >> 6;
            const float invf = powf(10000.0f, -(float)lr / 16.0f);
            #pragma unroll
            for (int i = 0; i < 4; ++i)
                #pragma unroll
                for (int r = 0; r < 4; ++r) {
                    long row = m0 + wm + i * 16 + lq * 4 + r;
                    int s = (int)row & 2047;
                    float ang = ((float)s / 40.0f) * invf;
                    float cv = cosf(ang), sv = sinf(ang);
                    float v0 = acc[i][0][r], v1 = acc[i][1][r];
                    float y[4] = { v0 * cv - v1 * sv, v1 * cv + v0 * sv,
                                   acc[i][2][r], acc[i][3][r] };
                    #pragma unroll
                    for (int j = 0; j < 4; ++j) {
                        int d = j * 16 + lr;
                        Cx[row * 1024 + h * 64 + d] = y[j];                   // krope fp32
                        Cy[row * 2048 + h * 128 + 64 + d] = (_Float16)y[j];   // k_flat rope half
                    }
                }
        }
    } else {  // epi_mode == 2
        if (zb == 0) {
            #pragma unroll
            for (int i = 0; i < 4; ++i)
                #pragma unroll
                for (int j = 0; j < 4; ++j)
                    #pragma unroll
                    for (int r = 0; r < 4; ++r) {
                        long row = m0 + wm + i * 16 + lq * 4 + r;
                        long col = n0 + wn + j * 16 + lr;
                        Ch[cofs + row * ldch + col] = (_Float16)acc[i][j][r];  // vT
                    }
        } else {
            const int mb = (int)m0 + wm;
            if (mb < 1024) {
                #pragma unroll
                for (int i = 0; i < 4; ++i)
                    #pragma unroll
                    for (int j = 0; j < 4; ++j)
                        #pragma unroll
                        for (int r = 0; r < 4; ++r) {
                            long u = m0 + wm + i * 16 + lq * 4 + r;
                            long col = n0 + wn + j * 16 + lr;
                            long qrow = ((u >> 6) << 7) + (u & 63);
                            Ch[cofs + qrow * 4096 + col] = (_Float16)acc[i][j][r];
                        }
            } else {
                const int h = (mb - 1024) >> 6;
                #pragma unroll
                for (int j = 0; j < 4; ++j)
                    #pragma unroll
                    for (int r = 0; r < 4; ++r) {
                        long col = n0 + wn + j * 16 + lr;
                        int s = (int)col & 2047;
                        int j16 = lq * 4 + r;
                        float ivf = powf(10000.0f, -(float)j16 / 16.0f);
                        float ang = ((float)s / 40.0f) * ivf;
                        float cv = cosf(ang), sv = sinf(ang);
                        float v0 = acc[0][j][r], v1 = acc[1][j][r];
                        float y[4] = { v0 * cv - v1 * sv, v1 * cv + v0 * sv,
                                       acc[2][j][r], acc[3][j][r] };
                        #pragma unroll
                        for (int i = 0; i < 4; ++i) {
                            int dd = i * 16 + lq * 4 + r;
                            long qrow = h * 128 + 64 + dd;
                            Ch[cofs + qrow * 4096 + col] = (_Float16)y[i];
                        }
                    }
            }
        }
    }
}

// ---- mega prep: 8 weight transposes (f32->f16 T) + 2 casts, one launch ----
__device__ inline void tr_tile(const float* __restrict__ in, _Float16* __restrict__ out,
                               int R, int C, int tile, int tx, int ty, float (*tb)[33])
{
    int tc = tile % (C >> 5), tr = tile / (C >> 5);
    int c0 = tc * 32, r0 = tr * 32;
    for (int i = ty; i < 32; i += 8)
        tb[i][tx] = in[(long)(r0 + i) * C + c0 + tx];
    __syncthreads();
    for (int i = ty; i < 32; i += 8)
        out[(long)(c0 + i) * R + r0 + tx] = (_Float16)tb[tx][i];
}

__device__ inline void cast_blk(const float* __restrict__ in, _Float16* __restrict__ out,
                                int blk, int tid)
{
    long idx = (long)blk * 2048 + tid * 8;
    float4 a = ((const float4*)(in + idx))[0];
    float4 b = ((const float4*)(in + idx))[1];
    half8 h = { (_Float16)a.x, (_Float16)a.y, (_Float16)a.z, (_Float16)a.w,
                (_Float16)b.x, (_Float16)b.y, (_Float16)b.z, (_Float16)b.w };
    *(half8*)(out + idx) = h;
}

__global__ void prep_kernel(
    const float* __restrict__ x, const float* __restrict__ W_dkv,
    const float* __restrict__ W_dq, const float* __restrict__ W_uk,
    const float* __restrict__ W_uv, const float* __restrict__ W_uq,
    const float* __restrict__ W_kr, const float* __restrict__ W_qr,
    const float* __restrict__ W_out,
    _Float16* __restrict__ WcatT, _Float16* __restrict__ WukT,
    _Float16* __restrict__ WuvT, _Float16* __restrict__ WuqcatT,
    _Float16* __restrict__ WqrT, _Float16* __restrict__ Wuqh,
    _Float16* __restrict__ WoutT, _Float16* __restrict__ xh)
{
    __shared__ float tb[32][33];
    int blk = blockIdx.x;
    int tid = threadIdx.x;
    int tx = tid & 31, ty = tid >> 5;
    if (blk < 2048)        tr_tile(W_dkv, WcatT,            2048, 1024, blk,         tx, ty, tb);
    else if (blk < 4096)   tr_tile(W_dq,  WcatT + 2097152,  2048, 1024, blk - 2048,  tx, ty, tb);
    else if (blk < 6144)   tr_tile(W_kr,  WcatT + 4194304,  2048, 1024, blk - 4096,  tx, ty, tb);
    else if (blk < 7168)   tr_tile(W_uk,  WukT,             1024, 1024, blk - 6144,  tx, ty, tb);
    else if (blk < 8192)   tr_tile(W_uq,  WuqcatT,          1024, 1024, blk - 7168,  tx, ty, tb);
    else if (blk < 9216)   tr_tile(W_qr,  WqrT,             1024, 1024, blk - 8192,  tx, ty, tb);
    else if (blk < 11264)  tr_tile(W_uv,  WuvT,             1024, 2048, blk - 9216,  tx, ty, tb);
    else if (blk < 15360)  tr_tile(W_out, WoutT,            2048, 2048, blk - 11264, tx, ty, tb);
    else if (blk < 19456)  cast_blk(x,    xh,   blk - 15360, tid);
    else                   cast_blk(W_uq, Wuqh, blk - 19456, tid);
}

// Mbuf16[i] = (f16) sum_{j<8} Mp[j*524288 + i]
__global__ void reduce8_cast_kernel(const float* __restrict__ in, _Float16* __restrict__ out)
{
    int i = blockIdx.x * 256 + threadIdx.x;   // 524288
    float s = 0.f;
    #pragma unroll
    for (int j = 0; j < 8; ++j) s += in[i + j * 524288];
    out[i] = (_Float16)s;
}

extern "C" void kernel_launch(void* const* d_in, const int* in_sizes, int n_in,
                              void* d_out, int out_size, void* d_ws, size_t ws_size,
                              hipStream_t stream)
{
    const float* x     = (const float*)d_in[0];
    const float* W_dkv = (const float*)d_in[1];
    const float* W_dq  = (const float*)d_in[2];
    const float* W_uk  = (const float*)d_in[3];
    const float* W_uv  = (const float*)d_in[4];
    const float* W_uq  = (const float*)d_in[5];
    const float* W_kr  = (const float*)d_in[6];
    const float* W_qr  = (const float*)d_in[7];
    const float* W_out = (const float*)d_in[8];

    float* out_main  = (float*)d_out;            // [2][2048][2048]
    float* out_ckv   = out_main + 8388608;       // [2][2048][1024]
    float* out_krope = out_ckv + 4194304;        // [2][2048][16][64]

    char* w = (char*)d_ws;
    size_t off = 0;
    auto alloc = [&](size_t bytes) { void* p = w + off; off += (bytes + 255) & ~(size_t)255; return p; };

    _Float16* catA    = (_Float16*)alloc(16777216);  // [4096][2048]: c_kv | c_q  (-> PT later)
    _Float16* WcatT   = (_Float16*)alloc(12582912);  // [3072][2048]: WdkvT|WdqT|WkrT
    _Float16* WukT    = (_Float16*)alloc(2097152);   // -> Mbuf16 after G5
    _Float16* WuvT    = (_Float16*)alloc(4194304);   // [2048][1024]   (adjacent to WuqcatT!)
    _Float16* WuqcatT = (_Float16*)alloc(4194304);   // rows 0-1023 WuqT, 1024-2047 WuqrT
    _Float16* WqrT    = (_Float16*)alloc(2097152);
    _Float16* Wuqh    = (_Float16*)alloc(2097152);
    _Float16* WoutT   = (_Float16*)alloc(8388608);   // [2048][2048]
    void*     reg_xm  = alloc(16777216);             // xh [4096][2048] -> Mbuf32p [8][524288] fp32
    _Float16* k_flat  = (_Float16*)alloc(16777216);  // [4096][2048]
    _Float16* vT      = (_Float16*)alloc(16777216);  // [2048][4096]   (adjacent to qT!)
    _Float16* qT      = (_Float16*)alloc(16777216);  // [2048][4096]

    _Float16* xh      = (_Float16*)reg_xm;
    float*    Mbuf32p = (float*)reg_xm;              // aliases xh (dead after G678)
    _Float16* PT      = catA;                        // aliases catA (dead after G678)
    _Float16* WuqrT   = WuqcatT + 1048576;
    _Float16* Mbuf16  = WukT;                        // aliases WukT (dead after G5)

    #define GF(A_,B_,Cf_,Ch_,Cx_,Cy_,M_,N_,Kc_,lda_,ldb_,ldcf_,ldch_,cmap_,cflo_,cfhi_,alpha_,nb_,nh_,nsk_,mode_,ab,ah,bb,bh,cb,ch2,cs) \
        hipLaunchKernelGGL(gemm_fast, dim3((N_)/128,(M_)/128,(nb_)*(nh_)*(nsk_)), dim3(256), 0, stream, \
            A_, B_, Cf_, Ch_, Cx_, Cy_, (int)(Kc_), (long)(lda_), (long)(ldb_), (long)(ldcf_), (long)(ldch_), \
            cmap_, (long)(cflo_), (long)(cfhi_), (float)(alpha_), nh_, nsk_, mode_, \
            (long)(ab),(long)(ah),(long)(bb),(long)(bh),(long)(cb),(long)(ch2),(long)(cs))

    #define GF128(A_,B_,Cf_,Ch_,Cx_,Cy_,M_,N_,Kc_,lda_,ldb_,ldcf_,ldch_,cmap_,cflo_,cfhi_,alpha_,nb_,nh_,nsk_,mode_,ab,ah,bb,bh,cb,ch2,cs) \
        hipLaunchKernelGGL(gemm128, dim3((N_)/128,(M_)/128,(nb_)*(nh_)*(nsk_)), dim3(256), 0, stream, \
            A_, B_, Cf_, Ch_, Cx_, Cy_, (int)(Kc_), (long)(lda_), (long)(ldb_), (long)(ldcf_), (long)(ldch_), \
            cmap_, (long)(cflo_), (long)(cfhi_), (float)(alpha_), nh_, nsk_, mode_, \
            (long)(ab),(long)(ah),(long)(bb),(long)(bh),(long)(cb),(long)(ch2),(long)(cs))

    // P0: mega prep (all transposes + casts), one launch
    hipLaunchKernelGGL(prep_kernel, dim3(19968), dim3(256), 0, stream,
        x, W_dkv, W_dq, W_uk, W_uv, W_uq, W_kr, W_qr, W_out,
        WcatT, WukT, WuvT, WuqcatT, WqrT, Wuqh, WoutT, xh);

    // G123 (mode 1, gemm128): [c_kv|c_q|k_r] = x @ WcatT   (768 blocks = 3.0/CU)
    GF128(xh, WcatT, out_ckv, catA, out_krope, k_flat, 4096, 3072, 2048, 2048, 2048, 0, 0,
       0, 0, 0, 1.0, 1, 1, 1, 1, 0,0,0,0,0,0,0);
    // G4: WuqrT = WqrT @ Wuqh  [1024 r][1024 cd]  (64 blocks, gemm_fast)
    GF(WqrT, Wuqh, (float*)nullptr, WuqrT, (float*)nullptr, (_Float16*)nullptr,
       1024, 1024, 1024, 1024, 1024, 0, 1024, 0, 0, 0, 1.0, 1, 1, 1, 0, 0,0,0,0,0,0,0);
    // G5 (gemm128): k_c content cols of k_flat (cmap); A = catA c_kv window  (256 blocks)
    GF128(catA, WukT, (float*)nullptr, k_flat, (float*)nullptr, (_Float16*)nullptr,
       4096, 1024, 1024, 2048, 1024, 0, 2048, 1, 0, 0, 1.0, 1, 1, 1, 0, 0,0,0,0,0,0,0);
    // G678 (mode 2, gemm128, z=2): z0 vT = WuvT @ c_kv^T; z1 qT assembly (+rope)  (1024 blocks = 4.0/CU)
    GF128(WuvT, catA, (float*)nullptr, vT, (float*)nullptr, (_Float16*)nullptr,
       2048, 4096, 1024, 1024, 2048, 0, 4096, 0, 0, 0, 1.0, 2, 1, 1, 2,
       2097152, 0, 1024, 0, 8388608, 0, 0);
    // G9: M partials (split-K 8): Mp[ks][b,h] = (1/sqrt128) qT_h @ vT_h^T chunk  (gemm_fast)
    GF(qT, vT, Mbuf32p, (_Float16*)nullptr, (float*)nullptr, (_Float16*)nullptr,
       128, 128, 256, 4096, 4096, 128, 0, 0, 0, 128, 0.08838834764831845, 2, 16, 8, 0,
       2048, 524288, 2048, 524288, 262144, 16384, 524288);
    hipLaunchKernelGGL(reduce8_cast_kernel, dim3(2048), dim3(256), 0, stream, Mbuf32p, Mbuf16);
    // G10: PT[b][o][h*128+dk] = WoutT_h @ M_h^T  (gemm_fast)
    GF(WoutT, Mbuf16, (float*)nullptr, PT, (float*)nullptr, (_Float16*)nullptr,
       2048, 128, 128, 2048, 128, 0, 2048, 0, 0, 0, 1.0, 2, 16, 1, 0,
       0, 128, 262144, 16384, 4194304, 128, 0);
    // G11 (mode 0, gemm128): output[b] = k_flat[b] @ PT[b]^T  (512 blocks = 2.0/CU)
    GF128(k_flat, PT, out_main, (_Float16*)nullptr, (float*)nullptr, (_Float16*)nullptr,
       2048, 2048, 2048, 2048, 2048, 2048, 0, 0, 0, 2048, 1.0, 2, 1, 1, 0,
       4194304, 0, 4194304, 0, 4194304, 0, 0);

    #undef GF
    #undef GF128
}

// Round 8
// 451.917 us; speedup vs baseline: 1.0548x; 1.0548x over previous
//
#include <hip/hip_runtime.h>
#include <math.h>

typedef _Float16 half8 __attribute__((ext_vector_type(8)));
typedef float floatx4 __attribute__((ext_vector_type(4)));

typedef const uint32_t __attribute__((address_space(1)))* gp1_t;
typedef uint32_t __attribute__((address_space(3)))* lp3_t;
#define GLDS16(g, l) __builtin_amdgcn_global_load_lds((gp1_t)(const void*)(g), (lp3_t)(void*)(l), 16, 0, 0)

#define BK 32

#define BARRIER() __builtin_amdgcn_s_barrier()
#define VM3()     asm volatile("s_waitcnt vmcnt(3)" ::: "memory")

// Bijective XCD-aware remap of linearized workgroup id (m204 form; identity when nwg<8).
__device__ inline int xcd_swz(int wg, int nwg)
{
    int q = nwg >> 3, r = nwg & 7;
    int xcd = wg & 7, idx = wg >> 3;
    return (xcd < r) ? (xcd * (q + 1) + idx) : (r * (q + 1) + (xcd - r) * q + idx);
}

// ---------------- 128x128 m97-structure kernel (G9 / G10 / G11) ----------------
// C[m][n] = alpha * sum_k A[m][k]*B[n][k]; A,B f16 k-contiguous.
__global__ __launch_bounds__(256) void gemm_fast(
    const _Float16* __restrict__ A, const _Float16* __restrict__ B,
    float* __restrict__ Cf, _Float16* __restrict__ Ch,
    float* __restrict__ Cx, _Float16* __restrict__ Cy,
    int Kc, long lda, long ldb, long ldcf, long ldch,
    int cmap, long cf_lo, long cf_hi, float alpha, int nh, int nsk, int epi_mode,
    long aoff_b, long aoff_h, long boff_b, long boff_h,
    long coff_b, long coff_h, long coff_s)
{
    __shared__ __align__(16) _Float16 As[128 * BK];
    __shared__ __align__(16) _Float16 Bs[128 * BK];

    const int z = blockIdx.z;
    const int hs = nh * nsk;
    const int zb = z / hs;
    const int rr = z % hs;
    const int zh = rr / nsk;
    const int ks = rr % nsk;

    const _Float16* Ab = A + (long)zb * aoff_b + (long)zh * aoff_h + (long)ks * Kc;
    const _Float16* Bb = B + (long)zb * boff_b + (long)zh * boff_h + (long)ks * Kc;
    const long cofs = (long)zb * coff_b + (long)zh * coff_h + (long)ks * coff_s;

    const int nwg = gridDim.x * gridDim.y;
    const int swz = xcd_swz(blockIdx.y * gridDim.x + blockIdx.x, nwg);
    const long m0 = (long)(swz / gridDim.x) * 128;
    const long n0 = (long)(swz % gridDim.x) * 128;
    const int t = threadIdx.x;
    const int wave = t >> 6, lane = t & 63;
    const int lr = lane & 15, lq = lane >> 4;
    const int wm = (wave & 1) * 64, wn = (wave >> 1) * 64;

    const int c0 = wave * 64 + lane;
    const int c1 = c0 + 256;
    const _Float16* ga0 = Ab + (m0 + (c0 >> 2)) * lda + (c0 & 3) * 8;
    const _Float16* ga1 = Ab + (m0 + (c1 >> 2)) * lda + (c1 & 3) * 8;
    const _Float16* gb0 = Bb + (n0 + (c0 >> 2)) * ldb + (c0 & 3) * 8;
    const _Float16* gb1 = Bb + (n0 + (c1 >> 2)) * ldb + (c1 & 3) * 8;
    _Float16* lA0 = As + wave * 512;
    _Float16* lA1 = As + 2048 + wave * 512;
    _Float16* lB0 = Bs + wave * 512;
    _Float16* lB1 = Bs + 2048 + wave * 512;

    floatx4 acc[4][4];
    #pragma unroll
    for (int i = 0; i < 4; ++i)
        #pragma unroll
        for (int j = 0; j < 4; ++j) acc[i][j] = (floatx4){0.f, 0.f, 0.f, 0.f};

    for (int k0 = 0; k0 < Kc; k0 += BK) {
        GLDS16(ga0, lA0); GLDS16(ga1, lA1);
        GLDS16(gb0, lB0); GLDS16(gb1, lB1);
        ga0 += BK; ga1 += BK; gb0 += BK; gb1 += BK;
        __syncthreads();

        half8 a[4], b[4];
        #pragma unroll
        for (int i = 0; i < 4; ++i) a[i] = *(const half8*)(As + (wm + i * 16 + lr) * BK + lq * 8);
        #pragma unroll
        for (int j = 0; j < 4; ++j) b[j] = *(const half8*)(Bs + (wn + j * 16 + lr) * BK + lq * 8);
        #pragma unroll
        for (int i = 0; i < 4; ++i)
            #pragma unroll
            for (int j = 0; j < 4; ++j)
                acc[i][j] = __builtin_amdgcn_mfma_f32_16x16x32_f16(a[i], b[j], acc[i][j], 0, 0, 0);
        __syncthreads();
    }

    // C/D layout: col = lane&15, row = (lane>>4)*4 + reg
    if (epi_mode == 0) {
        #pragma unroll
        for (int i = 0; i < 4; ++i)
            #pragma unroll
            for (int j = 0; j < 4; ++j)
                #pragma unroll
                for (int r = 0; r < 4; ++r) {
                    long row = m0 + wm + i * 16 + lq * 4 + r;
                    long col = n0 + wn + j * 16 + lr;
                    float v = alpha * acc[i][j][r];
                    if (Ch) {
                        long cm = cmap ? ((col >> 6) * 128 + (col & 63)) : col;
                        Ch[cofs + row * ldch + cm] = (_Float16)v;
                    }
                    if (Cf && col >= cf_lo && col < cf_hi)
                        Cf[cofs + row * ldcf + (col - cf_lo)] = v;
                }
    } else if (epi_mode == 1) {
        const int nb = (int)n0 + wn;
        if (nb < 2048) {
            #pragma unroll
            for (int i = 0; i < 4; ++i)
                #pragma unroll
                for (int j = 0; j < 4; ++j)
                    #pragma unroll
                    for (int r = 0; r < 4; ++r) {
                        long row = m0 + wm + i * 16 + lq * 4 + r;
                        long col = n0 + wn + j * 16 + lr;
                        float v = acc[i][j][r];
                        Ch[row * 2048 + col] = (_Float16)v;
                        if (nb < 1024) Cf[row * 1024 + col] = v;
                    }
        } else {
            const int h = (nb - 2048) >> 6;
            const float invf = powf(10000.0f, -(float)lr / 16.0f);
            #pragma unroll
            for (int i = 0; i < 4; ++i)
                #pragma unroll
                for (int r = 0; r < 4; ++r) {
                    long row = m0 + wm + i * 16 + lq * 4 + r;
                    int s = (int)row & 2047;
                    float ang = ((float)s / 40.0f) * invf;
                    float cv = cosf(ang), sv = sinf(ang);
                    float v0 = acc[i][0][r], v1 = acc[i][1][r];
                    float y[4] = { v0 * cv - v1 * sv, v1 * cv + v0 * sv,
                                   acc[i][2][r], acc[i][3][r] };
                    #pragma unroll
                    for (int j = 0; j < 4; ++j) {
                        int d = j * 16 + lr;
                        Cx[row * 1024 + h * 64 + d] = y[j];
                        Cy[row * 2048 + h * 128 + 64 + d] = (_Float16)y[j];
                    }
                }
        }
    } else {  // epi_mode == 2
        if (zb == 0) {
            #pragma unroll
            for (int i = 0; i < 4; ++i)
                #pragma unroll
                for (int j = 0; j < 4; ++j)
                    #pragma unroll
                    for (int r = 0; r < 4; ++r) {
                        long row = m0 + wm + i * 16 + lq * 4 + r;
                        long col = n0 + wn + j * 16 + lr;
                        Ch[cofs + row * ldch + col] = (_Float16)acc[i][j][r];
                    }
        } else {
            const int mb = (int)m0 + wm;
            if (mb < 1024) {
                #pragma unroll
                for (int i = 0; i < 4; ++i)
                    #pragma unroll
                    for (int j = 0; j < 4; ++j)
                        #pragma unroll
                        for (int r = 0; r < 4; ++r) {
                            long u = m0 + wm + i * 16 + lq * 4 + r;
                            long col = n0 + wn + j * 16 + lr;
                            long qrow = ((u >> 6) << 7) + (u & 63);
                            Ch[cofs + qrow * 4096 + col] = (_Float16)acc[i][j][r];
                        }
            } else {
                const int h = (mb - 1024) >> 6;
                #pragma unroll
                for (int j = 0; j < 4; ++j)
                    #pragma unroll
                    for (int r = 0; r < 4; ++r) {
                        long col = n0 + wn + j * 16 + lr;
                        int s = (int)col & 2047;
                        int j16 = lq * 4 + r;
                        float ivf = powf(10000.0f, -(float)j16 / 16.0f);
                        float ang = ((float)s / 40.0f) * ivf;
                        float cv = cosf(ang), sv = sinf(ang);
                        float v0 = acc[0][j][r], v1 = acc[1][j][r];
                        float y[4] = { v0 * cv - v1 * sv, v1 * cv + v0 * sv,
                                       acc[2][j][r], acc[3][j][r] };
                        #pragma unroll
                        for (int i = 0; i < 4; ++i) {
                            int dd = i * 16 + lq * 4 + r;
                            long qrow = h * 128 + 64 + dd;
                            Ch[cofs + qrow * 4096 + col] = (_Float16)y[i];
                        }
                    }
            }
        }
    }
}

// ---------------- 256x128 counted-vmcnt kernel with z-packed secondary GEMM ----------------
// grid = (N/128, gy, z), block = 512 (8 waves, 4M x 2N, 64x64 per wave). Primary runs
// for z < zsplit with XCD-swizzled (bx,by) over gridDim.x x pgy (blocks with by>=pgy
// exit). Secondary (z >= zsplit) is an independent small GEMM (A2,B2 -> Ch2, epi0 +
// optional cmap) tiled 256x128 over (mlim2 x nlim2) raw block ids — lets small GEMMs
// (G4, G5) ride inside big launches on otherwise-idle CUs (single-stream concurrency).
// LDS: 3 slots x 24 KiB (A 16 units + B 8 units; unit = 16 rows x 32 k = 512 halves;
// lane l holds (row=l&15, k=(l>>4)*8..+7) at halves l*8) -> GLDS16 linear write from
// per-lane-permuted global src (m173); fragment ds_read_b128 at unit+lane*16B:
// conflict-free both sides (proven r2-r7, SQ_LDS_BANK_CONFLICT=0).
// Body tt: {3x stage tile tt+2 -> slot (tt+2)%3 ; 8x ds_read slot tt%3 ; 16 MFMA ;
// vmcnt(3) ; barrier}. VM3 leaves only tile tt+2's 3 loads in flight -> tile tt+1
// landed across all waves at barrier release; slot distance 2 mod 3 -> no overwrite
// race; vmcnt never 0 in-loop (T4). Tail tile indices clamp into [0,NT).
__global__ __launch_bounds__(512, 4) void gemm256(
    const _Float16* __restrict__ A, const _Float16* __restrict__ B,
    float* __restrict__ Cf, _Float16* __restrict__ Ch,
    float* __restrict__ Cx, _Float16* __restrict__ Cy,
    int Kc, long lda, long ldb, long ldcf, long ldch,
    int cmap, long cf_lo, long cf_hi, float alpha, int nh, int nsk, int epi_mode,
    long aoff_b, long aoff_h, long boff_b, long boff_h,
    long coff_b, long coff_h, long coff_s,
    int zsplit, int pgy,
    const _Float16* __restrict__ A2, const _Float16* __restrict__ B2,
    _Float16* __restrict__ Ch2,
    int Kc2, long lda2, long ldb2, long ldch2, int mlim2, int nlim2, int cmap2)
{
    __shared__ __align__(16) _Float16 sm[36864];   // 72 KiB: 3 slots x (A 8K + B 4K halves)

    const int z = blockIdx.z;
    int zbv = 0;
    long m0, n0, cofs = 0;
    const _Float16 *Ab, *Bb;

    if (z >= zsplit) {
        // secondary GEMM: raw block ids, bounds-checked (uniform early exit, pre-barrier)
        if ((int)blockIdx.x >= nlim2 || (int)blockIdx.y >= mlim2) return;
        Ab = A2; Bb = B2;
        Kc = Kc2; lda = lda2; ldb = ldb2;
        Ch = Ch2; ldch = ldch2; Cf = nullptr;
        cmap = cmap2; alpha = 1.0f; epi_mode = 0;
        m0 = (long)blockIdx.y * 256;
        n0 = (long)blockIdx.x * 128;
    } else {
        if ((int)blockIdx.y >= pgy) return;
        const int hs = nh * nsk;
        zbv = z / hs;
        const int rr = z % hs;
        const int zh = rr / nsk;
        const int ks = rr % nsk;
        Ab = A + (long)zbv * aoff_b + (long)zh * aoff_h + (long)ks * Kc;
        Bb = B + (long)zbv * boff_b + (long)zh * boff_h + (long)ks * Kc;
        cofs = (long)zbv * coff_b + (long)zh * coff_h + (long)ks * coff_s;
        const int nwg = gridDim.x * pgy;
        const int swz = xcd_swz((int)blockIdx.y * gridDim.x + blockIdx.x, nwg);
        m0 = (long)(swz / gridDim.x) * 256;
        n0 = (long)(swz % gridDim.x) * 128;
    }

    const int t = threadIdx.x;
    const int wave = t >> 6, lane = t & 63;
    const int lr = lane & 15, lq = lane >> 4;
    const int wm = (wave >> 1) * 64, wn = (wave & 1) * 64;   // 4M x 2N wave grid
    const int wmrb = (wave >> 1) * 4, wnrb = (wave & 1) * 4;
    const int NT = Kc >> 5;                                  // K-tiles of 32

    floatx4 acc[4][4];
    #pragma unroll
    for (int i = 0; i < 4; ++i)
        #pragma unroll
        for (int j = 0; j < 4; ++j) acc[i][j] = (floatx4){0.f, 0.f, 0.f, 0.f};

    // one staging issue per thread = 1 LDS unit per wave; q 0,1 -> A units wave*2+q,
    // q==2 -> B unit wave. Tail tile index clamped into [0,NT).
#define ST(tt_, q_, sl_) do { \
        const int tcl_ = (tt_) < NT ? (tt_) : (tt_) - NT; \
        const int isB_ = ((q_) == 2); \
        const int u_ = isB_ ? wave : wave * 2 + (q_); \
        const long grow_ = (isB_ ? n0 : m0) + u_ * 16 + lr; \
        const _Float16* src_ = (isB_ ? Bb + grow_ * ldb : Ab + grow_ * lda) \
                               + (long)tcl_ * 32 + lq * 8; \
        _Float16* dst_ = sm + (sl_) * 12288 + (isB_ ? 8192 : 0) + u_ * 512; \
        GLDS16(src_, dst_); \
    } while (0)

#define LOADA(sl_) { _Pragma("unroll") \
    for (int i_ = 0; i_ < 4; ++i_) \
        aF[i_] = *(const half8*)(sm + (sl_) * 12288 + (wmrb + i_) * 512 + lane * 8); }
#define LOADB(sl_) { _Pragma("unroll") \
    for (int j_ = 0; j_ < 4; ++j_) \
        bF[j_] = *(const half8*)(sm + (sl_) * 12288 + 8192 + (wnrb + j_) * 512 + lane * 8); }
#define MFMA16() { _Pragma("unroll") \
    for (int i_ = 0; i_ < 4; ++i_) { _Pragma("unroll") \
        for (int j_ = 0; j_ < 4; ++j_) \
            acc[i_][j_] = __builtin_amdgcn_mfma_f32_16x16x32_f16(aF[i_], bF[j_], acc[i_][j_], 0, 0, 0); } }

    // prologue: stage tiles 0 (slot 0) and 1 (slot 1); drain to 3 => tile 0 landed
    ST(0, 0, 0); ST(0, 1, 0); ST(0, 2, 0);
    ST(1, 0, 1); ST(1, 1, 1); ST(1, 2, 1);
    VM3(); BARRIER();

    half8 aF[4], bF[4];
    int sc = 0, ss = 2;
    for (int tt = 0; tt < NT; ++tt) {
        ST(tt + 2, 0, ss); ST(tt + 2, 1, ss); ST(tt + 2, 2, ss);
        LOADA(sc); LOADB(sc);
        __builtin_amdgcn_s_setprio(1); MFMA16(); __builtin_amdgcn_s_setprio(0);
        VM3();       // tile tt+1 landed (all waves after barrier)
        BARRIER();
        sc = (sc == 2) ? 0 : sc + 1;
        ss = (ss == 2) ? 0 : ss + 1;
    }
#undef ST
#undef LOADA
#undef LOADB
#undef MFMA16

    // ---- epilogues (identical per-wave 64x64 geometry to gemm_fast) ----
    if (epi_mode == 0) {
        #pragma unroll
        for (int i = 0; i < 4; ++i)
            #pragma unroll
            for (int j = 0; j < 4; ++j)
                #pragma unroll
                for (int r = 0; r < 4; ++r) {
                    long row = m0 + wm + i * 16 + lq * 4 + r;
                    long col = n0 + wn + j * 16 + lr;
                    float v = alpha * acc[i][j][r];
                    if (Ch) {
                        long cm = cmap ? ((col >> 6) * 128 + (col & 63)) : col;
                        Ch[cofs + row * ldch + cm] = (_Float16)v;
                    }
                    if (Cf && col >= cf_lo && col < cf_hi)
                        Cf[cofs + row * ldcf + (col - cf_lo)] = v;
                }
    } else if (epi_mode == 1) {
        const int nb = (int)n0 + wn;   // 64-aligned -> wave-uniform branches
        if (nb < 2048) {
            #pragma unroll
            for (int i = 0; i < 4; ++i)
                #pragma unroll
                for (int j = 0; j < 4; ++j)
                    #pragma unroll
                    for (int r = 0; r < 4; ++r) {
                        long row = m0 + wm + i * 16 + lq * 4 + r;
                        long col = n0 + wn + j * 16 + lr;
                        float v = acc[i][j][r];
                        Ch[row * 2048 + col] = (_Float16)v;      // catA (c_kv|c_q)
                        if (nb < 1024) Cf[row * 1024 + col] = v; // c_kv fp32
                    }
        } else {
            const int h = (nb - 2048) >> 6;
            const float invf = powf(10000.0f, -(float)lr / 16.0f);
            #pragma unroll
            for (int i = 0; i < 4; ++i)
                #pragma unroll
                for (int r = 0; r < 4; ++r) {
                    long row = m0 + wm + i * 16 + lq * 4 + r;
                    int s = (int)row & 2047;
                    float ang = ((float)s / 40.0f) * invf;
                    float cv = cosf(ang), sv = sinf(ang);
                    float v0 = acc[i][0][r], v1 = acc[i][1][r];
                    float y[4] = { v0 * cv - v1 * sv, v1 * cv + v0 * sv,
                                   acc[i][2][r], acc[i][3][r] };
                    #pragma unroll
                    for (int j = 0; j < 4; ++j) {
                        int d = j * 16 + lr;
                        Cx[row * 1024 + h * 64 + d] = y[j];                   // krope fp32
                        Cy[row * 2048 + h * 128 + 64 + d] = (_Float16)y[j];   // k_flat rope half
                    }
                }
        }
    } else {  // epi_mode == 2
        if (zbv == 0) {
            #pragma unroll
            for (int i = 0; i < 4; ++i)
                #pragma unroll
                for (int j = 0; j < 4; ++j)
                    #pragma unroll
                    for (int r = 0; r < 4; ++r) {
                        long row = m0 + wm + i * 16 + lq * 4 + r;
                        long col = n0 + wn + j * 16 + lr;
                        Ch[cofs + row * ldch + col] = (_Float16)acc[i][j][r];  // vT
                    }
        } else {
            const int mb = (int)m0 + wm;   // 64-aligned -> wave-uniform
            if (mb < 1024) {
                #pragma unroll
                for (int i = 0; i < 4; ++i)
                    #pragma unroll
                    for (int j = 0; j < 4; ++j)
                        #pragma unroll
                        for (int r = 0; r < 4; ++r) {
                            long u = m0 + wm + i * 16 + lq * 4 + r;
                            long col = n0 + wn + j * 16 + lr;
                            long qrow = ((u >> 6) << 7) + (u & 63);
                            Ch[cofs + qrow * 4096 + col] = (_Float16)acc[i][j][r];
                        }
            } else {
                const int h = (mb - 1024) >> 6;   // wave spans exactly 1 head (64 rows)
                #pragma unroll
                for (int j = 0; j < 4; ++j)
                    #pragma unroll
                    for (int r = 0; r < 4; ++r) {
                        long col = n0 + wn + j * 16 + lr;
                        int s = (int)col & 2047;
                        int j16 = lq * 4 + r;
                        float ivf = powf(10000.0f, -(float)j16 / 16.0f);
                        float ang = ((float)s / 40.0f) * ivf;
                        float cv = cosf(ang), sv = sinf(ang);
                        float v0 = acc[0][j][r], v1 = acc[1][j][r];
                        float y[4] = { v0 * cv - v1 * sv, v1 * cv + v0 * sv,
                                       acc[2][j][r], acc[3][j][r] };
                        #pragma unroll
                        for (int i = 0; i < 4; ++i) {
                            int dd = i * 16 + lq * 4 + r;
                            long qrow = h * 128 + 64 + dd;
                            Ch[cofs + qrow * 4096 + col] = (_Float16)y[i];
                        }
                    }
            }
        }
    }
}

// ---- mega prep: 8 weight transposes (f32->f16 T) + 2 casts, one launch ----
__device__ inline void tr_tile(const float* __restrict__ in, _Float16* __restrict__ out,
                               int R, int C, int tile, int tx, int ty, float (*tb)[33])
{
    int tc = tile % (C >> 5), tr = tile / (C >> 5);
    int c0 = tc * 32, r0 = tr * 32;
    for (int i = ty; i < 32; i += 8)
        tb[i][tx] = in[(long)(r0 + i) * C + c0 + tx];
    __syncthreads();
    for (int i = ty; i < 32; i += 8)
        out[(long)(c0 + i) * R + r0 + tx] = (_Float16)tb[tx][i];
}

__device__ inline void cast_blk(const float* __restrict__ in, _Float16* __restrict__ out,
                                int blk, int tid)
{
    long idx = (long)blk * 2048 + tid * 8;
    float4 a = ((const float4*)(in + idx))[0];
    float4 b = ((const float4*)(in + idx))[1];
    half8 h = { (_Float16)a.x, (_Float16)a.y, (_Float16)a.z, (_Float16)a.w,
                (_Float16)b.x, (_Float16)b.y, (_Float16)b.z, (_Float16)b.w };
    *(half8*)(out + idx) = h;
}

__global__ void prep_kernel(
    const float* __restrict__ x, const float* __restrict__ W_dkv,
    const float* __restrict__ W_dq, const float* __restrict__ W_uk,
    const float* __restrict__ W_uv, const float* __restrict__ W_uq,
    const float* __restrict__ W_kr, const float* __restrict__ W_qr,
    const float* __restrict__ W_out,
    _Float16* __restrict__ WcatT, _Float16* __restrict__ WukT,
    _Float16* __restrict__ WuvT, _Float16* __restrict__ WuqcatT,
    _Float16* __restrict__ WqrT, _Float16* __restrict__ Wuqh,
    _Float16* __restrict__ WoutT, _Float16* __restrict__ xh)
{
    __shared__ float tb[32][33];
    int blk = blockIdx.x;
    int tid = threadIdx.x;
    int tx = tid & 31, ty = tid >> 5;
    if (blk < 2048)        tr_tile(W_dkv, WcatT,            2048, 1024, blk,         tx, ty, tb);
    else if (blk < 4096)   tr_tile(W_dq,  WcatT + 2097152,  2048, 1024, blk - 2048,  tx, ty, tb);
    else if (blk < 6144)   tr_tile(W_kr,  WcatT + 4194304,  2048, 1024, blk - 4096,  tx, ty, tb);
    else if (blk < 7168)   tr_tile(W_uk,  WukT,             1024, 1024, blk - 6144,  tx, ty, tb);
    else if (blk < 8192)   tr_tile(W_uq,  WuqcatT,          1024, 1024, blk - 7168,  tx, ty, tb);
    else if (blk < 9216)   tr_tile(W_qr,  WqrT,             1024, 1024, blk - 8192,  tx, ty, tb);
    else if (blk < 11264)  tr_tile(W_uv,  WuvT,             1024, 2048, blk - 9216,  tx, ty, tb);
    else if (blk < 15360)  tr_tile(W_out, WoutT,            2048, 2048, blk - 11264, tx, ty, tb);
    else if (blk < 19456)  cast_blk(x,    xh,   blk - 15360, tid);
    else                   cast_blk(W_uq, Wuqh, blk - 19456, tid);
}

// Mbuf16[i] = (f16) sum_{j<8} Mp[j*524288 + i]
__global__ void reduce8_cast_kernel(const float* __restrict__ in, _Float16* __restrict__ out)
{
    int i = blockIdx.x * 256 + threadIdx.x;   // 524288
    float s = 0.f;
    #pragma unroll
    for (int j = 0; j < 8; ++j) s += in[i + j * 524288];
    out[i] = (_Float16)s;
}

extern "C" void kernel_launch(void* const* d_in, const int* in_sizes, int n_in,
                              void* d_out, int out_size, void* d_ws, size_t ws_size,
                              hipStream_t stream)
{
    const float* x     = (const float*)d_in[0];
    const float* W_dkv = (const float*)d_in[1];
    const float* W_dq  = (const float*)d_in[2];
    const float* W_uk  = (const float*)d_in[3];
    const float* W_uv  = (const float*)d_in[4];
    const float* W_uq  = (const float*)d_in[5];
    const float* W_kr  = (const float*)d_in[6];
    const float* W_qr  = (const float*)d_in[7];
    const float* W_out = (const float*)d_in[8];

    float* out_main  = (float*)d_out;            // [2][2048][2048]
    float* out_ckv   = out_main + 8388608;       // [2][2048][1024]
    float* out_krope = out_ckv + 4194304;        // [2][2048][16][64]

    char* w = (char*)d_ws;
    size_t off = 0;
    auto alloc = [&](size_t bytes) { void* p = w + off; off += (bytes + 255) & ~(size_t)255; return p; };

    _Float16* catA    = (_Float16*)alloc(16777216);  // [4096][2048]: c_kv | c_q  (-> PT later)
    _Float16* WcatT   = (_Float16*)alloc(12582912);  // [3072][2048]: WdkvT|WdqT|WkrT
    _Float16* WukT    = (_Float16*)alloc(2097152);   // -> Mbuf16 after G5
    _Float16* WuvT    = (_Float16*)alloc(4194304);   // [2048][1024]   (adjacent to WuqcatT!)
    _Float16* WuqcatT = (_Float16*)alloc(4194304);   // rows 0-1023 WuqT, 1024-2047 WuqrT
    _Float16* WqrT    = (_Float16*)alloc(2097152);
    _Float16* Wuqh    = (_Float16*)alloc(2097152);
    _Float16* WoutT   = (_Float16*)alloc(8388608);   // [2048][2048]
    void*     reg_xm  = alloc(16777216);             // xh [4096][2048] -> Mbuf32p [8][524288] fp32
    _Float16* k_flat  = (_Float16*)alloc(16777216);  // [4096][2048]
    _Float16* vT      = (_Float16*)alloc(16777216);  // [2048][4096]   (adjacent to qT!)
    _Float16* qT      = (_Float16*)alloc(16777216);  // [2048][4096]

    _Float16* xh      = (_Float16*)reg_xm;
    float*    Mbuf32p = (float*)reg_xm;              // aliases xh (dead after G678)
    _Float16* PT      = catA;                        // aliases catA (dead after G678)
    _Float16* WuqrT   = WuqcatT + 1048576;
    _Float16* Mbuf16  = WukT;                        // aliases WukT (dead after G5)

    #define GF(A_,B_,Cf_,Ch_,Cx_,Cy_,M_,N_,Kc_,lda_,ldb_,ldcf_,ldch_,cmap_,cflo_,cfhi_,alpha_,nb_,nh_,nsk_,mode_,ab,ah,bb,bh,cb,ch2,cs) \
        hipLaunchKernelGGL(gemm_fast, dim3((N_)/128,(M_)/128,(nb_)*(nh_)*(nsk_)), dim3(256), 0, stream, \
            A_, B_, Cf_, Ch_, Cx_, Cy_, (int)(Kc_), (long)(lda_), (long)(ldb_), (long)(ldcf_), (long)(ldch_), \
            cmap_, (long)(cflo_), (long)(cfhi_), (float)(alpha_), nh_, nsk_, mode_, \
            (long)(ab),(long)(ah),(long)(bb),(long)(bh),(long)(cb),(long)(ch2),(long)(cs))

    // P0: mega prep (all transposes + casts), one launch
    hipLaunchKernelGGL(prep_kernel, dim3(19968), dim3(256), 0, stream,
        x, W_dkv, W_dq, W_uk, W_uv, W_uq, W_kr, W_qr, W_out,
        WcatT, WukT, WuvT, WuqcatT, WqrT, Wuqh, WoutT, xh);

    // G123 (mode 1, 256x128) + z-packed G4 secondary:
    //   primary z=0: [c_kv|c_q|k_r] = x @ WcatT  (grid 24x16, 384 blocks)
    //   secondary z=1: WuqrT = WqrT @ Wuqh  (bx<8, by<4 -> 32 blocks of 256x128)
    hipLaunchKernelGGL(gemm256, dim3(24, 16, 2), dim3(512), 0, stream,
        xh, WcatT, out_ckv, catA, out_krope, k_flat,
        2048, (long)2048, (long)2048, (long)0, (long)0,
        0, (long)0, (long)0, 1.0f, 1, 1, 1,
        (long)0, (long)0, (long)0, (long)0, (long)0, (long)0, (long)0,
        1 /*zsplit*/, 16 /*pgy*/,
        WqrT, Wuqh, WuqrT, 1024, (long)1024, (long)1024, (long)1024, 4, 8, 0);

    // G678 (mode 2, 256x128, z=2) + z-packed G5 secondary:
    //   primary z0: vT = WuvT @ c_kv^T; z1: qT assembly (+rope)  (grid 32x8 used, pgy=8)
    //   secondary z=2: k_c cols of k_flat = catA(c_kv) @ WukT (cmap; bx<8, by<16 -> 128 blocks)
    hipLaunchKernelGGL(gemm256, dim3(32, 16, 3), dim3(512), 0, stream,
        WuvT, catA, (float*)nullptr, vT, (float*)nullptr, (_Float16*)nullptr,
        1024, (long)1024, (long)2048, (long)0, (long)4096,
        0, (long)0, (long)0, 1.0f, 1, 1, 2,
        (long)2097152, (long)0, (long)1024, (long)0, (long)8388608, (long)0, (long)0,
        2 /*zsplit*/, 8 /*pgy*/,
        catA, WukT, k_flat, 1024, (long)2048, (long)1024, (long)2048, 16, 8, 1);

    // G9: M partials (split-K 8): Mp[ks][b,h] = (1/sqrt128) qT_h @ vT_h^T chunk  (gemm_fast)
    GF(qT, vT, Mbuf32p, (_Float16*)nullptr, (float*)nullptr, (_Float16*)nullptr,
       128, 128, 256, 4096, 4096, 128, 0, 0, 0, 128, 0.08838834764831845, 2, 16, 8, 0,
       2048, 524288, 2048, 524288, 262144, 16384, 524288);
    hipLaunchKernelGGL(reduce8_cast_kernel, dim3(2048), dim3(256), 0, stream, Mbuf32p, Mbuf16);
    // G10: PT[b][o][h*128+dk] = WoutT_h @ M_h^T  (gemm_fast)
    GF(WoutT, Mbuf16, (float*)nullptr, PT, (float*)nullptr, (_Float16*)nullptr,
       2048, 128, 128, 2048, 128, 0, 2048, 0, 0, 0, 1.0, 2, 16, 1, 0,
       0, 128, 262144, 16384, 4194304, 128, 0);
    // G11 (mode 0, gemm_fast: 512 blocks = 2/CU machine fill)
    GF(k_flat, PT, out_main, (_Float16*)nullptr, (float*)nullptr, (_Float16*)nullptr,
       2048, 2048, 2048, 2048, 2048, 2048, 0, 0, 0, 2048, 1.0, 2, 1, 1, 0,
       4194304, 0, 4194304, 0, 4194304, 0, 0);

    #undef GF
}